// Round 16
// baseline (175.597 us; speedup 1.0000x reference)
//
#include <hip/hip_runtime.h>
#include <hip/hip_bf16.h>
#include <cstdint>

// ---------------------------------------------------------------------------
// MultiHeadAttention: B=2, T=2048, D=1024, H=16, hd=64, causal.
// Inputs (fp32): x[B,T,D], W_qkv[3D,D], b_qkv[3D], W_out[D,D], b_out[D]
// out (fp32): [B,T,D]
// ws big path (48MB): Q@0, K@8M, Vtb@16M, O@24M, xb@32M, Wqkvb@40M, Woutb@46M
// GEMMs: one-shot fp32->bf16 cvt (single fused kernel).
// Softmax: no-max flash (p = exp2(s) directly), in-lane f32 row-sum.
// v16: gemm_qkv BARRIER-FREE. All prior grafts (swizzle/dbuf/counted-vmcnt/
//   BK=64) were null because every one kept the block-wide barrier convoy
//   (m233: ~72% of 2-phase cost). Now: 4 independent waves, each owning its
//   64x64 tile + private 16KB LDS dbuf (BK=32), staging via global_load_lds,
//   ZERO __syncthreads in the loop; per-wave counted vmcnt(8) only.
//   Within-wave RAW: 2 stages in flight, wait oldest 8. WAR: ds_reads are
//   MFMA-consumed (lgkm) before the re-stage issues in program order (LDS
//   aliasing order preserved). LDS 64KB -> 2 blocks/CU (8 indep waves/CU).
//   A/B staged per-wave (2x L2 traffic, 18 < 34.5 TB/s OK). v9 line-pair
//   swizzle on fragment reads (2 lanes/bank = free, verified).
// History: v6 coalesced LDS staging (attn 68->38); v7 attn dbuf (177.5);
// v8 fused transpose_v (173.1); v9 swizzle (conflicts 3.15M->0); v10 dbuf
// (170.3); v11 counted vmcnt (null); v12 attn occupancy (null); v13 BK=64
// (null); v14 gemm_out BN=64 2 blocks/CU (165.4, best).
// LESSONS: launch_bounds 2nd arg = min-BLOCKS/CU ((512,4) = 64-VGPR cap =
// spills); hipcc host pass lacks gfx950 builtins -> #if inside bodies (R5);
// isolated grafts null while the barrier convoy dominates (v9-v13).
// ---------------------------------------------------------------------------

using short8  = __attribute__((ext_vector_type(8))) short;
using floatx4 = __attribute__((ext_vector_type(4))) float;

#define LDS_STRIDE 40  // legacy gemm tiles: 32+8 pad

__device__ __forceinline__ float bf16_to_f32(unsigned short u) {
    union { unsigned int i; float f; } v; v.i = ((unsigned int)u) << 16; return v.f;
}
__device__ __forceinline__ unsigned short f32_to_bf16(float f) {
    union { float f; unsigned int i; } v; v.f = f;
    unsigned int x = v.i;
    unsigned int r = x + 0x7FFFu + ((x >> 16) & 1u);  // RNE
    return (unsigned short)(r >> 16);
}
__device__ __forceinline__ short8 cvt8(const float* __restrict__ p) {
    const float4 f0 = *(const float4*)p;
    const float4 f1 = *(const float4*)(p + 4);
    short8 r;
    r[0] = (short)f32_to_bf16(f0.x); r[1] = (short)f32_to_bf16(f0.y);
    r[2] = (short)f32_to_bf16(f0.z); r[3] = (short)f32_to_bf16(f0.w);
    r[4] = (short)f32_to_bf16(f1.x); r[5] = (short)f32_to_bf16(f1.y);
    r[6] = (short)f32_to_bf16(f1.z); r[7] = (short)f32_to_bf16(f1.w);
    return r;
}
// pack two f32 -> one dword of 2 bf16 (RNE); no builtin on gfx950, pure-VALU asm
__device__ __forceinline__ unsigned int cvtpk(float a, float b) {
    unsigned int r;
    asm("v_cvt_pk_bf16_f32 %0, %1, %2" : "=v"(r) : "v"(a), "v"(b));
    return r;
}

// 1/sqrt(64) * log2(e)
#define Q_PRESCALE 0.1803368801111204f

#if __has_builtin(__builtin_amdgcn_global_load_lds)
#define ASYNC_STAGE 1
typedef const __attribute__((address_space(1))) void* gas1_t;
typedef __attribute__((address_space(3))) void* las3_t;
#else
#define ASYNC_STAGE 0
#endif

// Defined unconditionally: hipcc's host pass lacks the builtin, so the #if
// must live INSIDE the body (placeholder branch never executes on device).
__device__ __forceinline__ void gload_lds16(const ushort* g, ushort* l) {
#if ASYNC_STAGE
    __builtin_amdgcn_global_load_lds((gas1_t)g, (las3_t)l, 16, 0, 0);
#else
    *(short8*)l = *(const short8*)g;  // host-pass placeholder
#endif
}

// inverse of transpose_v's slot->key map: which Vtb slot holds key k (0..63)
__device__ __forceinline__ int v_slot(int k) {
    const int k5 = k & 31;
    return (k & 32) + ((k5 >> 4) & 1) * 4 + ((k5 >> 2) & 3) * 8 + (k5 & 3);
}

// fused fp32 -> bf16 for x / W_qkv / W_out, 8 elems/thread, one launch.
// Range boundaries are block-aligned: 524288 = 2048*256, 917504 = 3584*256.
__global__ __launch_bounds__(256, 8) void cvt_bf16_3(
    const float* __restrict__ x,  const float* __restrict__ wq,
    const float* __restrict__ wo, ushort* __restrict__ xb,
    ushort* __restrict__ wqb, ushort* __restrict__ wob)
{
    const int i = blockIdx.x * 256 + threadIdx.x;  // 0..1048575
    const float* src; ushort* dst; int off;
    if (i < 524288)      { src = x;  dst = xb;  off = i; }
    else if (i < 917504) { src = wq; dst = wqb; off = i - 524288; }
    else                 { src = wo; dst = wob; off = i - 917504; }
    *(short8*)(dst + (size_t)off * 8) = cvt8(src + (size_t)off * 8);
}

// ===== v16 QKV GEMM: barrier-free independent waves =====================
// Block 256 thr = 4 waves, wave tile 64x64 at (wm,wn); each wave has a
// PRIVATE 16KB LDS slice: A dbuf (2x 64x32) + B dbuf. BK=32, 32 K-steps,
// no __syncthreads in the loop; per-wave counted vmcnt only.
// LDS tiles use the line-pair swizzle (v9, verified 0 conflicts): logical
// (row, 8-ushort chunk c) lives at line=row>>1, slot=((row&1)*4+c)^(line&7).
// Epilogue: scatter Q (scaled), K [bh][t][64]; V into tile-blocked permuted
// Vtb[bh][t64][d][slot] (transpose_v fused).
__global__ __launch_bounds__(256, 2) void gemm_qkv(
    const ushort* __restrict__ A, const ushort* __restrict__ W,
    const float* __restrict__ bias,
    ushort* __restrict__ Cq, ushort* __restrict__ Ck, ushort* __restrict__ Cv,
    int M, int N, int K)
{
    __shared__ __align__(16) ushort S[4][8192];  // per-wave: A0 A1 B0 B1 (2048 each)

    const int tid  = threadIdx.x;
    const int lane = tid & 63;
    const int wave = tid >> 6;
    const int wm = (wave >> 1) * 64;
    const int wn = (wave & 1) * 64;
    const int m0 = blockIdx.x * 128;
    const int n0 = blockIdx.y * 128;
    const int quad = lane >> 4;
    const int l16  = lane & 15;
    ushort* Sw = &S[wave][0];

    floatx4 acc[4][4];
#pragma unroll
    for (int i = 0; i < 4; i++)
#pragma unroll
        for (int j = 0; j < 4; j++) acc[i][j] = (floatx4)0.0f;

    // staging source map (per wave): pass p covers LDS bytes
    // [lane*16 + p*1024, +16) of a 4KB tile buffer. Decode physical->logical:
    // line = ob>>7, slot = (ob>>4)&7, pp = slot^(line&7),
    // row = line*2 + (pp>>2), chunk = pp&3.
    const ushort* pA[4];
    const ushort* pB[4];
#pragma unroll
    for (int p = 0; p < 4; p++) {
        const int ob   = lane * 16 + p * 1024;
        const int line = ob >> 7;
        const int pp   = ((ob >> 4) & 7) ^ (line & 7);
        const int row  = line * 2 + (pp >> 2);
        const int ch   = pp & 3;
        pA[p] = A + (size_t)(m0 + wm + row) * K + ch * 8;
        pB[p] = W + (size_t)(n0 + wn + row) * K + ch * 8;
    }

    auto stage = [&](int k0, int buf) {
        ushort* da = Sw + buf * 2048;
        ushort* db = Sw + 4096 + buf * 2048;
#pragma unroll
        for (int p = 0; p < 4; p++) {
            gload_lds16(pA[p] + k0, da + p * 512);
            gload_lds16(pB[p] + k0, db + p * 512);
        }
    };

    // fragment read offset (local row = i*16 + l16, chunk = quad); slot is
    // i-invariant ((row+16)>>1 keeps line&7, row&1) -> step = i*512 ushorts.
    const int foff = (l16 >> 1) * 64 +
                     (((((l16 & 1) << 2) + quad) ^ ((l16 >> 1) & 7)) << 3);

    auto compute = [&](int buf) {
        const ushort* a = Sw + buf * 2048;
        const ushort* b = Sw + 4096 + buf * 2048;
        short8 af[4], bf[4];
#pragma unroll
        for (int i = 0; i < 4; i++) af[i] = *(const short8*)&a[foff + i * 512];
#pragma unroll
        for (int j = 0; j < 4; j++) bf[j] = *(const short8*)&b[foff + j * 512];
#pragma unroll
        for (int i = 0; i < 4; i++)
#pragma unroll
            for (int j = 0; j < 4; j++)
                acc[i][j] = __builtin_amdgcn_mfma_f32_16x16x32_bf16(af[i], bf[j], acc[i][j], 0, 0, 0);
    };

#if ASYNC_STAGE
    // Per-wave pipeline, 2 stages (8 loads each) in flight, no barriers.
    // At iter t: outstanding = stage(t) + stage(t+1) = 16 -> vmcnt(8) waits
    // exactly for stage(t). Last iter (only stage(t) left): vmcnt(0).
    const int NT = K >> 5;  // 32; NT >= 2
    stage(0, 0);
    stage(32, 1);
    int buf = 0;
    for (int t = 0; t < NT; ++t) {
        if (t + 1 < NT) {
            asm volatile("s_waitcnt vmcnt(8)" ::: "memory");
        } else {
            asm volatile("s_waitcnt vmcnt(0)" ::: "memory");
        }
        compute(buf);
        if (t + 2 < NT) stage((t + 2) * 32, buf);  // reuse just-consumed buf
        buf ^= 1;
    }
#else
    for (int k0 = 0; k0 < K; k0 += 32) {
        // host-pass placeholder path (never used on device)
        stage(k0, 0);
        __syncthreads();
        compute(0);
        __syncthreads();
    }
#endif

#pragma unroll
    for (int i = 0; i < 4; i++) {
#pragma unroll
        for (int j = 0; j < 4; j++) {
#pragma unroll
            for (int r = 0; r < 4; r++) {
                const int row = m0 + wm + i * 16 + quad * 4 + r;
                const int col = n0 + wn + j * 16 + l16;
                float v = acc[i][j][r] + bias[col];
                const int h  = col / 192;
                const int rr = col - h * 192;
                const int sel = rr >> 6;
                const int d   = rr & 63;
                const int b = row >> 11;
                const int t = row & 2047;
                const int bh = b * 16 + h;
                if (sel == 0) {
                    Cq[(((size_t)bh) * 2048 + t) * 64 + d] =
                        f32_to_bf16(v * Q_PRESCALE);
                } else if (sel == 1) {
                    Ck[(((size_t)bh) * 2048 + t) * 64 + d] = f32_to_bf16(v);
                } else {
                    // fused transpose_v: Vtb[bh][t>>6][d][slot(t&63)]
                    Cv[(((size_t)bh * 32 + (t >> 6)) * 64 + d) * 64 + v_slot(t & 63)] =
                        f32_to_bf16(v);
                }
            }
        }
    }
}

// ===== v14 out-proj GEMM, BM=128 BN=64 BK=64: Cout = A @ W^T + bias ======
// Grid (32,16) = 512 blocks -> 2 blocks/CU (8 waves/CU). 2x2 waves, wave
// tile 64x32, acc[4][2]. v13-style swizzle/staging.
__global__ __launch_bounds__(256, 3) void gemm_out(
    const ushort* __restrict__ A, const ushort* __restrict__ W,
    const float* __restrict__ bias, float* __restrict__ Cout,
    int M, int N, int K)
{
    __shared__ __align__(16) ushort As[128 * 64];
    __shared__ __align__(16) ushort Bs[64 * 64];

    const int tid  = threadIdx.x;
    const int lane = tid & 63;
    const int wave = tid >> 6;
    const int wm = (wave >> 1) * 64;   // 0 or 64
    const int wn = (wave & 1) * 32;    // 0 or 32
    const int m0 = blockIdx.x * 128;
    const int n0 = blockIdx.y * 64;
    const int quad = lane >> 4;
    const int l16  = lane & 15;

    floatx4 acc[4][2];
#pragma unroll
    for (int i = 0; i < 4; i++)
#pragma unroll
        for (int j = 0; j < 2; j++) acc[i][j] = (floatx4)0.0f;

    const int rb  = tid >> 3;
    const int lch = (tid & 7) ^ (rb & 7);
    const ushort* pA = A + (size_t)(m0 + rb) * K + lch * 8;
    const ushort* pB = W + (size_t)(n0 + rb) * K + lch * 8;  // rb<64 rows for B passes
    const size_t cstep = (size_t)32 * K;

    const int Ra = wm + l16;
    const int aoff0 = Ra * 64 + ((quad       ^ (Ra & 7)) << 3);
    const int aoff1 = Ra * 64 + (((4 + quad) ^ (Ra & 7)) << 3);
    const int Rb = wn + l16;
    const int boff0 = Rb * 64 + ((quad       ^ (Rb & 7)) << 3);
    const int boff1 = Rb * 64 + (((4 + quad) ^ (Rb & 7)) << 3);

    for (int k0 = 0; k0 < K; k0 += 64) {
        __syncthreads();
#pragma unroll
        for (int c = 0; c < 4; c++)
            gload_lds16(pA + c * cstep + k0, &As[c * 2048 + wave * 512]);
#pragma unroll
        for (int c = 0; c < 2; c++)
            gload_lds16(pB + c * cstep + k0, &Bs[c * 2048 + wave * 512]);
        __syncthreads();

        short8 af0[4], af1[4];
#pragma unroll
        for (int i = 0; i < 4; i++) {
            af0[i] = *(const short8*)&As[aoff0 + i * 1024];
            af1[i] = *(const short8*)&As[aoff1 + i * 1024];
        }
#pragma unroll
        for (int j = 0; j < 2; j++) {
            const short8 bf0 = *(const short8*)&Bs[boff0 + j * 1024];
            const short8 bf1 = *(const short8*)&Bs[boff1 + j * 1024];
#pragma unroll
            for (int i = 0; i < 4; i++) {
                acc[i][j] = __builtin_amdgcn_mfma_f32_16x16x32_bf16(af0[i], bf0, acc[i][j], 0, 0, 0);
                acc[i][j] = __builtin_amdgcn_mfma_f32_16x16x32_bf16(af1[i], bf1, acc[i][j], 0, 0, 0);
            }
        }
    }

#pragma unroll
    for (int i = 0; i < 4; i++) {
#pragma unroll
        for (int j = 0; j < 2; j++) {
#pragma unroll
            for (int r = 0; r < 4; r++) {
                const int row = m0 + wm + i * 16 + quad * 4 + r;
                const int col = n0 + wn + j * 16 + l16;
                Cout[(size_t)row * N + col] = acc[i][j][r] + bias[col];
            }
        }
    }
}

// ===== legacy fused-cvt GEMM (fallback when ws < 48MB) =====
template <int MODE, int AFP32>
__global__ __launch_bounds__(256, 2) void gemm_bt(
    const void* __restrict__ Av, const float* __restrict__ W,
    const float* __restrict__ bias,
    ushort* __restrict__ Cq, ushort* __restrict__ Ck, ushort* __restrict__ Cv,
    float* __restrict__ Cout, int M, int N, int K)
{
    __shared__ __align__(16) ushort As[128 * LDS_STRIDE];
    __shared__ __align__(16) ushort Bs[128 * LDS_STRIDE];

    const int tid  = threadIdx.x;
    const int lane = tid & 63;
    const int wave = tid >> 6;
    const int wm = (wave >> 1) * 64;
    const int wn = (wave & 1) * 64;
    const int m0 = blockIdx.x * 128;
    const int n0 = blockIdx.y * 128;
    const int quad = lane >> 4;
    const int l16  = lane & 15;

    floatx4 acc[4][4];
#pragma unroll
    for (int i = 0; i < 4; i++)
#pragma unroll
        for (int j = 0; j < 4; j++) acc[i][j] = (floatx4)0.0f;

    const int srow = tid >> 2;
    const int scol = (tid & 3) * 8;

    for (int k0 = 0; k0 < K; k0 += 32) {
        short8 a0, a1;
        if (AFP32) {
            const float* A = (const float*)Av;
            a0 = cvt8(A + (size_t)(m0 + srow) * K + k0 + scol);
            a1 = cvt8(A + (size_t)(m0 + srow + 64) * K + k0 + scol);
        } else {
            const ushort* A = (const ushort*)Av;
            a0 = *(const short8*)(A + (size_t)(m0 + srow) * K + k0 + scol);
            a1 = *(const short8*)(A + (size_t)(m0 + srow + 64) * K + k0 + scol);
        }
        const short8 b0 = cvt8(W + (size_t)(n0 + srow) * K + k0 + scol);
        const short8 b1 = cvt8(W + (size_t)(n0 + srow + 64) * K + k0 + scol);
        __syncthreads();
        *(short8*)&As[srow * LDS_STRIDE + scol] = a0;
        *(short8*)&As[(srow + 64) * LDS_STRIDE + scol] = a1;
        *(short8*)&Bs[srow * LDS_STRIDE + scol] = b0;
        *(short8*)&Bs[(srow + 64) * LDS_STRIDE + scol] = b1;
        __syncthreads();

        short8 af[4], bf[4];
#pragma unroll
        for (int i = 0; i < 4; i++)
            af[i] = *(const short8*)&As[(wm + i * 16 + l16) * LDS_STRIDE + quad * 8];
#pragma unroll
        for (int j = 0; j < 4; j++)
            bf[j] = *(const short8*)&Bs[(wn + j * 16 + l16) * LDS_STRIDE + quad * 8];
#pragma unroll
        for (int i = 0; i < 4; i++)
#pragma unroll
            for (int j = 0; j < 4; j++)
                acc[i][j] = __builtin_amdgcn_mfma_f32_16x16x32_bf16(af[i], bf[j], acc[i][j], 0, 0, 0);
    }

#pragma unroll
    for (int i = 0; i < 4; i++) {
#pragma unroll
        for (int j = 0; j < 4; j++) {
#pragma unroll
            for (int r = 0; r < 4; r++) {
                const int row = m0 + wm + i * 16 + quad * 4 + r;
                const int col = n0 + wn + j * 16 + l16;
                float v = acc[i][j][r] + bias[col];
                if (MODE == 0) {
                    const int h  = col / 192;
                    const int rr = col - h * 192;
                    const int sel = rr >> 6;
                    const int d   = rr & 63;
                    const int b = row >> 11;
                    const int t = row & 2047;
                    const int bh = b * 16 + h;
                    if (sel == 0) {
                        Cq[(((size_t)bh) * 2048 + t) * 64 + d] =
                            f32_to_bf16(v * Q_PRESCALE);
                    } else if (sel == 1) {
                        Ck[(((size_t)bh) * 2048 + t) * 64 + d] = f32_to_bf16(v);
                    } else {
                        Cv[(((size_t)bh * 32 + (t >> 6)) * 64 + d) * 64 + v_slot(t & 63)] =
                            f32_to_bf16(v);
                    }
                } else {
                    Cout[(size_t)row * N + col] = v;
                }
            }
        }
    }
}

// ===========================================================================
// MFMA causal flash attention, v12 (unchanged): 64-row q-blocks, 4 blocks/CU,
// KVBLK=64 dbuf LDS 32KB, per-CU step count exactly constant, swapped QK^T
// register-P body, kf/vf lifetime split. Grid 1024 = 32 bh x 32 qtiles.
// ===========================================================================
__global__ __launch_bounds__(256, 4) void attn_mfma(
    const ushort* __restrict__ Q, const ushort* __restrict__ K,
    const ushort* __restrict__ Vtb, ushort* __restrict__ O)
{
    const int bid   = blockIdx.x;
    const int bh    = bid & 31;
    const int qtIdx = bid >> 5;                       // 0..31
    const int qi    = (qtIdx < 16) ? (31 - qtIdx) : (qtIdx - 16);
    const int tid  = threadIdx.x;
    const int wave = tid >> 6;
    const int lane = tid & 63;
    const int quad = lane >> 4;
    const int l16  = lane & 15;
    const int qb   = qi * 64 + wave * 16;

    __shared__ __align__(16) ushort Ks[2][4096];  // 64 keys x 64 ush (swz)
    __shared__ __align__(16) ushort Vs[2][4096];

    const size_t kbase = (size_t)bh * 2048 * 64;

    const int ob0 = tid * 16, ob1 = ob0 + 4096;
    const int r0 = ob0 >> 7, c0 = (ob0 >> 4) & 7;
    const int r1 = ob1 >> 7, c1 = (ob1 >> 4) & 7;
    const int e0 = r0 * 64 + ((c0 ^ (r0 & 7)) << 3);  // ushort idx in tile
    const int e1 = r1 * 64 + ((c1 ^ (r1 & 7)) << 3);
    const ushort* Kb = K + kbase;                      // + t*4096 + e
    const ushort* Vb = Vtb + (size_t)bh * 32 * 4096;   // + t*4096 + e

    auto stage = [&](int t, ushort* KsB, ushort* VsB) {
        const ushort* Ktile = Kb + t * 4096;
        const ushort* Vtile = Vb + t * 4096;
        gload_lds16(Ktile + e0, KsB + wave * 512);
        gload_lds16(Ktile + e1, KsB + 2048 + wave * 512);
        gload_lds16(Vtile + e0, VsB + wave * 512);
        gload_lds16(Vtile + e1, VsB + 2048 + wave * 512);
    };

    const int sw0 = ((quad ^ (l16 & 7)) << 3);        // half 0: C = quad
    const int sw1 = (((4 + quad) ^ (l16 & 7)) << 3);  // half 1: C = 4+quad
    const int rbase = l16 * 64;

    short8 qf0, qf1;
    {
        const ushort* qp = Q + kbase + (size_t)(qb + l16) * 64 + quad * 8;
        qf0 = *(const short8*)qp;
        qf1 = *(const short8*)(qp + 32);
    }

    floatx4 accO[4];
#pragma unroll
    for (int d = 0; d < 4; d++) accO[d] = (floatx4)0.0f;
    float accLs = 0.0f;

    union PB { unsigned int u[4]; short8 s8; };

    auto compute = [&](int t, const ushort* KsB, const ushort* VsB) {
        short8 kf[4][2];
#pragma unroll
        for (int j = 0; j < 4; j++) {
            kf[j][0] = *(const short8*)&KsB[j * 1024 + rbase + sw0];
            kf[j][1] = *(const short8*)&KsB[j * 1024 + rbase + sw1];
        }
        floatx4 sc[4];
#pragma unroll
        for (int j = 0; j < 4; j++) {
            floatx4 acc = (floatx4)0.0f;
            acc = __builtin_amdgcn_mfma_f32_16x16x32_bf16(kf[j][0], qf0, acc, 0, 0, 0);
            acc = __builtin_amdgcn_mfma_f32_16x16x32_bf16(kf[j][1], qf1, acc, 0, 0, 0);
            sc[j] = acc;
        }
        if (t * 64 + 63 > qb) {  // diagonal tile: causal mask
            const int qcol = qb + l16;
#pragma unroll
            for (int j = 0; j < 4; j++) {
                const int keyb = t * 64 + j * 16 + quad * 4;
#pragma unroll
                for (int r = 0; r < 4; r++)
                    if (keyb + r > qcol) sc[j][r] = -1e30f;
            }
        }
#pragma unroll
        for (int j = 0; j < 4; j++)
#pragma unroll
            for (int r = 0; r < 4; r++)
                sc[j][r] = __builtin_amdgcn_exp2f(sc[j][r]);
        const floatx4 ssum = sc[0] + sc[1] + sc[2] + sc[3];
        accLs += (ssum[0] + ssum[1]) + (ssum[2] + ssum[3]);
        PB p0, p1;
#pragma unroll
        for (int j = 0; j < 2; j++) {
            p0.u[j * 2 + 0] = cvtpk(sc[j][0], sc[j][1]);
            p0.u[j * 2 + 1] = cvtpk(sc[j][2], sc[j][3]);
            p1.u[j * 2 + 0] = cvtpk(sc[j + 2][0], sc[j + 2][1]);
            p1.u[j * 2 + 1] = cvtpk(sc[j + 2][2], sc[j + 2][3]);
        }
        short8 vf[4][2];
#pragma unroll
        for (int d = 0; d < 4; d++) {
            vf[d][0] = *(const short8*)&VsB[d * 1024 + rbase + sw0];
            vf[d][1] = *(const short8*)&VsB[d * 1024 + rbase + sw1];
        }
#pragma unroll
        for (int d = 0; d < 4; d++) {
            accO[d] = __builtin_amdgcn_mfma_f32_16x16x32_bf16(p0.s8, vf[d][0], accO[d], 0, 0, 0);
            accO[d] = __builtin_amdgcn_mfma_f32_16x16x32_bf16(p1.s8, vf[d][1], accO[d], 0, 0, 0);
        }
    };

    const int nt = qi + 1;  // 64-key steps
    stage(0, Ks[0], Vs[0]);
    __syncthreads();        // buf0 staged
    int t = 0;
    while (true) {
        if (t + 1 < nt) stage(t + 1, Ks[1], Vs[1]);  // prefetch under compute
        compute(t, Ks[0], Vs[0]);
        __syncthreads();    // prefetch landed + all waves done with buf0
        if (++t >= nt) break;
        if (t + 1 < nt) stage(t + 1, Ks[0], Vs[0]);
        compute(t, Ks[1], Vs[1]);
        __syncthreads();
        if (++t >= nt) break;
    }

    const int b = bh >> 4, h = bh & 15;
    {
        float L = accLs;
        L += __shfl_xor(L, 16);
        L += __shfl_xor(L, 32);  // now L(q=l16) in all quads
        float inv[4];
#pragma unroll
        for (int r = 0; r < 4; r++) inv[r] = 1.0f / __shfl(L, quad * 4 + r);
#pragma unroll
        for (int d = 0; d < 4; d++)
#pragma unroll
            for (int r = 0; r < 4; r++)
                O[(size_t)(b * 2048 + qb + quad * 4 + r) * 1024 + h * 64 + d * 16 + l16] =
                    f32_to_bf16(accO[d][r] * inv[r]);
    }
}

extern "C" void kernel_launch(void* const* d_in, const int* in_sizes, int n_in,
                              void* d_out, int out_size, void* d_ws, size_t ws_size,
                              hipStream_t stream) {
    const float* x    = (const float*)d_in[0];
    const float* Wqkv = (const float*)d_in[1];
    const float* bqkv = (const float*)d_in[2];
    const float* Wout = (const float*)d_in[3];
    const float* bout = (const float*)d_in[4];
    float* out = (float*)d_out;

    char* ws = (char*)d_ws;
    const size_t MB = 1024 * 1024;
    ushort* Q    = (ushort*)(ws + 0 * MB);
    ushort* Kk   = (ushort*)(ws + 8 * MB);
    ushort* Vtb  = (ushort*)(ws + 16 * MB);  // tile-blocked permuted V (direct)
    ushort* O    = (ushort*)(ws + 24 * MB);

    const dim3 blk(256);
    if (ws_size >= 48 * MB) {
        ushort* xb    = (ushort*)(ws + 32 * MB);
        ushort* Wqkvb = (ushort*)(ws + 40 * MB);
        ushort* Woutb = (ushort*)(ws + 46 * MB);
        cvt_bf16_3<<<dim3(4096), blk, 0, stream>>>(x, Wqkv, Wout, xb, Wqkvb, Woutb);
        gemm_qkv<<<dim3(32, 24), blk, 0, stream>>>(xb, Wqkvb, bqkv, Q, Kk, Vtb,
                                                   4096, 3072, 1024);
        attn_mfma<<<dim3(1024), blk, 0, stream>>>(Q, Kk, Vtb, O);
        gemm_out<<<dim3(32, 16), blk, 0, stream>>>(O, Woutb, bout, out,
                                                   4096, 1024, 1024);
    } else {
        gemm_bt<0, 1><<<dim3(32, 24), blk, 0, stream>>>(x, Wqkv, bqkv, Q, Kk, Vtb,
                                                        nullptr, 4096, 3072, 1024);
        attn_mfma<<<dim3(1024), blk, 0, stream>>>(Q, Kk, Vtb, O);
        gemm_bt<1, 0><<<dim3(32, 8), blk, 0, stream>>>(O, Wout, bout, nullptr, nullptr,
                                                       nullptr, out, 4096, 1024, 1024);
    }
}

// Round 17
// 163.367 us; speedup vs baseline: 1.0749x; 1.0749x over previous
//
#include <hip/hip_runtime.h>
#include <hip/hip_bf16.h>
#include <cstdint>

// ---------------------------------------------------------------------------
// MultiHeadAttention: B=2, T=2048, D=1024, H=16, hd=64, causal.
// Inputs (fp32): x[B,T,D], W_qkv[3D,D], b_qkv[3D], W_out[D,D], b_out[D]
// out (fp32): [B,T,D]
// ws big path (48MB): Q@0, K@8M, Vtb@16M, O@24M, xb@32M, Wqkvb@40M, Woutb@46M
// GEMMs: one-shot fp32->bf16 cvt (single fused kernel).
// Softmax: no-max flash (p = exp2(s) directly), in-lane f32 row-sum.
// v17 = REVERT to v14 (measured best, 165.4us). v16's barrier-free waves
//   regressed gemm_qkv 42.5->60us: private 64KB LDS halved blocks/CU (3->2)
//   and per-wave staging 4x'd VMEM issue per wave — lost more than the
//   barriers cost. Conclusion: the 128^2 plateau (~42.5us, MfmaUtil 22%) is
//   issue-rate-bound at this tile shape; 5 structural variants all >= 42.2.
// Final config: gemm_qkv = v13 BK=64 single-buf swizzled (3 blocks/CU);
//   gemm_out = v14 BN=64 (2 blocks/CU); attn = v12 (4 blocks/CU, balanced);
//   cvt = fused single launch.
// History: v6 coalesced LDS staging (attn 68->38); v7 attn dbuf (177.5);
// v8 fused transpose_v (173.1); v9 swizzle (conflicts 3.15M->0); v10 dbuf
// (170.3); v11 counted vmcnt (null); v12 attn occupancy (null); v13 BK=64
// (null); v14 gemm_out BN=64 (165.4, best); v16 barrier-free (regressed).
// LESSONS: launch_bounds 2nd arg = min-BLOCKS/CU ((512,4) = 64-VGPR cap =
// spills); hipcc host pass lacks gfx950 builtins -> #if inside bodies (R5);
// isolated grafts null at 2-phase structures; barrier removal loses to
// occupancy + shared-staging amortization (v16).
// ---------------------------------------------------------------------------

using short8  = __attribute__((ext_vector_type(8))) short;
using floatx4 = __attribute__((ext_vector_type(4))) float;

#define LDS_STRIDE 40  // legacy gemm tiles: 32+8 pad

__device__ __forceinline__ float bf16_to_f32(unsigned short u) {
    union { unsigned int i; float f; } v; v.i = ((unsigned int)u) << 16; return v.f;
}
__device__ __forceinline__ unsigned short f32_to_bf16(float f) {
    union { float f; unsigned int i; } v; v.f = f;
    unsigned int x = v.i;
    unsigned int r = x + 0x7FFFu + ((x >> 16) & 1u);  // RNE
    return (unsigned short)(r >> 16);
}
__device__ __forceinline__ short8 cvt8(const float* __restrict__ p) {
    const float4 f0 = *(const float4*)p;
    const float4 f1 = *(const float4*)(p + 4);
    short8 r;
    r[0] = (short)f32_to_bf16(f0.x); r[1] = (short)f32_to_bf16(f0.y);
    r[2] = (short)f32_to_bf16(f0.z); r[3] = (short)f32_to_bf16(f0.w);
    r[4] = (short)f32_to_bf16(f1.x); r[5] = (short)f32_to_bf16(f1.y);
    r[6] = (short)f32_to_bf16(f1.z); r[7] = (short)f32_to_bf16(f1.w);
    return r;
}
// pack two f32 -> one dword of 2 bf16 (RNE); no builtin on gfx950, pure-VALU asm
__device__ __forceinline__ unsigned int cvtpk(float a, float b) {
    unsigned int r;
    asm("v_cvt_pk_bf16_f32 %0, %1, %2" : "=v"(r) : "v"(a), "v"(b));
    return r;
}

// 1/sqrt(64) * log2(e)
#define Q_PRESCALE 0.1803368801111204f

#if __has_builtin(__builtin_amdgcn_global_load_lds)
#define ASYNC_STAGE 1
typedef const __attribute__((address_space(1))) void* gas1_t;
typedef __attribute__((address_space(3))) void* las3_t;
#else
#define ASYNC_STAGE 0
#endif

// Defined unconditionally: hipcc's host pass lacks the builtin, so the #if
// must live INSIDE the body (placeholder branch never executes on device).
__device__ __forceinline__ void gload_lds16(const ushort* g, ushort* l) {
#if ASYNC_STAGE
    __builtin_amdgcn_global_load_lds((gas1_t)g, (las3_t)l, 16, 0, 0);
#else
    *(short8*)l = *(const short8*)g;  // host-pass placeholder
#endif
}

// inverse of transpose_v's slot->key map: which Vtb slot holds key k (0..63)
__device__ __forceinline__ int v_slot(int k) {
    const int k5 = k & 31;
    return (k & 32) + ((k5 >> 4) & 1) * 4 + ((k5 >> 2) & 3) * 8 + (k5 & 3);
}

// fused fp32 -> bf16 for x / W_qkv / W_out, 8 elems/thread, one launch.
// Range boundaries are block-aligned: 524288 = 2048*256, 917504 = 3584*256.
__global__ __launch_bounds__(256, 8) void cvt_bf16_3(
    const float* __restrict__ x,  const float* __restrict__ wq,
    const float* __restrict__ wo, ushort* __restrict__ xb,
    ushort* __restrict__ wqb, ushort* __restrict__ wob)
{
    const int i = blockIdx.x * 256 + threadIdx.x;  // 0..1048575
    const float* src; ushort* dst; int off;
    if (i < 524288)      { src = x;  dst = xb;  off = i; }
    else if (i < 917504) { src = wq; dst = wqb; off = i - 524288; }
    else                 { src = wo; dst = wob; off = i - 917504; }
    *(short8*)(dst + (size_t)off * 8) = cvt8(src + (size_t)off * 8);
}

// ===== bf16 GEMM, BK=64 single-buffered (v13): C = A @ W^T, QKV only =====
// Scatter Q (scaled), K [bh][t][64]; V directly into tile-blocked permuted
// Vtb[bh][t64][d][slot] (transpose_v fused).
// LDS tiles [128][64] ushorts, swizzle: physical (row r, 16B chunk ch) holds
// logical (r, ch ^ (r&7)). 16 K-steps, 2 barriers/step, 3 blocks/CU.
__global__ __launch_bounds__(256, 3) void gemm_qkv(
    const ushort* __restrict__ A, const ushort* __restrict__ W,
    const float* __restrict__ bias,
    ushort* __restrict__ Cq, ushort* __restrict__ Ck, ushort* __restrict__ Cv,
    int M, int N, int K)
{
    __shared__ __align__(16) ushort As[128 * 64];
    __shared__ __align__(16) ushort Bs[128 * 64];

    const int tid  = threadIdx.x;
    const int lane = tid & 63;
    const int wave = tid >> 6;
    const int wm = (wave >> 1) * 64;
    const int wn = (wave & 1) * 64;
    const int m0 = blockIdx.x * 128;
    const int n0 = blockIdx.y * 128;
    const int quad = lane >> 4;
    const int l16  = lane & 15;

    floatx4 acc[4][4];
#pragma unroll
    for (int i = 0; i < 4; i++)
#pragma unroll
        for (int j = 0; j < 4; j++) acc[i][j] = (floatx4)0.0f;

    // staging map: pass c (0..3): thread covers LDS ushorts [c*2048+tid*8,+8)
    // -> r = c*32 + (tid>>3), logical chunk = (tid&7) ^ ((tid>>3)&7).
    const int rb  = tid >> 3;
    const int lch = (tid & 7) ^ (rb & 7);
    const ushort* pA = A + (size_t)(m0 + rb) * K + lch * 8;
    const ushort* pB = W + (size_t)(n0 + rb) * K + lch * 8;
    const size_t cstep = (size_t)32 * K;

    // swizzled fragment read offsets; (R+16)&7 == R&7 -> step i*1024.
    const int Ra = wm + l16;
    const int aoff0 = Ra * 64 + ((quad       ^ (Ra & 7)) << 3);
    const int aoff1 = Ra * 64 + (((4 + quad) ^ (Ra & 7)) << 3);
    const int Rb = wn + l16;
    const int boff0 = Rb * 64 + ((quad       ^ (Rb & 7)) << 3);
    const int boff1 = Rb * 64 + (((4 + quad) ^ (Rb & 7)) << 3);

    for (int k0 = 0; k0 < K; k0 += 64) {
        __syncthreads();  // prev step's fragment reads done
#pragma unroll
        for (int c = 0; c < 4; c++) {
            gload_lds16(pA + c * cstep + k0, &As[c * 2048 + wave * 512]);
            gload_lds16(pB + c * cstep + k0, &Bs[c * 2048 + wave * 512]);
        }
        __syncthreads();  // compiler drains vmcnt before barrier

        short8 af0[4], af1[4];
#pragma unroll
        for (int i = 0; i < 4; i++) {
            af0[i] = *(const short8*)&As[aoff0 + i * 1024];
            af1[i] = *(const short8*)&As[aoff1 + i * 1024];
        }
#pragma unroll
        for (int j = 0; j < 4; j++) {
            const short8 bf0 = *(const short8*)&Bs[boff0 + j * 1024];
            const short8 bf1 = *(const short8*)&Bs[boff1 + j * 1024];
#pragma unroll
            for (int i = 0; i < 4; i++) {
                acc[i][j] = __builtin_amdgcn_mfma_f32_16x16x32_bf16(af0[i], bf0, acc[i][j], 0, 0, 0);
                acc[i][j] = __builtin_amdgcn_mfma_f32_16x16x32_bf16(af1[i], bf1, acc[i][j], 0, 0, 0);
            }
        }
    }

#pragma unroll
    for (int i = 0; i < 4; i++) {
#pragma unroll
        for (int j = 0; j < 4; j++) {
#pragma unroll
            for (int r = 0; r < 4; r++) {
                const int row = m0 + wm + i * 16 + quad * 4 + r;
                const int col = n0 + wn + j * 16 + l16;
                float v = acc[i][j][r] + bias[col];
                const int h  = col / 192;
                const int rr = col - h * 192;
                const int sel = rr >> 6;
                const int d   = rr & 63;
                const int b = row >> 11;
                const int t = row & 2047;
                const int bh = b * 16 + h;
                if (sel == 0) {
                    Cq[(((size_t)bh) * 2048 + t) * 64 + d] =
                        f32_to_bf16(v * Q_PRESCALE);
                } else if (sel == 1) {
                    Ck[(((size_t)bh) * 2048 + t) * 64 + d] = f32_to_bf16(v);
                } else {
                    // fused transpose_v: Vtb[bh][t>>6][d][slot(t&63)]
                    Cv[(((size_t)bh * 32 + (t >> 6)) * 64 + d) * 64 + v_slot(t & 63)] =
                        f32_to_bf16(v);
                }
            }
        }
    }
}

// ===== v14 out-proj GEMM, BM=128 BN=64 BK=64: Cout = A @ W^T + bias ======
// Grid (32,16) = 512 blocks -> 2 blocks/CU (8 waves/CU). 2x2 waves, wave
// tile 64x32, acc[4][2]. v13-style swizzle/staging.
__global__ __launch_bounds__(256, 3) void gemm_out(
    const ushort* __restrict__ A, const ushort* __restrict__ W,
    const float* __restrict__ bias, float* __restrict__ Cout,
    int M, int N, int K)
{
    __shared__ __align__(16) ushort As[128 * 64];
    __shared__ __align__(16) ushort Bs[64 * 64];

    const int tid  = threadIdx.x;
    const int lane = tid & 63;
    const int wave = tid >> 6;
    const int wm = (wave >> 1) * 64;   // 0 or 64
    const int wn = (wave & 1) * 32;    // 0 or 32
    const int m0 = blockIdx.x * 128;
    const int n0 = blockIdx.y * 64;
    const int quad = lane >> 4;
    const int l16  = lane & 15;

    floatx4 acc[4][2];
#pragma unroll
    for (int i = 0; i < 4; i++)
#pragma unroll
        for (int j = 0; j < 2; j++) acc[i][j] = (floatx4)0.0f;

    const int rb  = tid >> 3;
    const int lch = (tid & 7) ^ (rb & 7);
    const ushort* pA = A + (size_t)(m0 + rb) * K + lch * 8;
    const ushort* pB = W + (size_t)(n0 + rb) * K + lch * 8;  // rb<64 rows for B passes
    const size_t cstep = (size_t)32 * K;

    const int Ra = wm + l16;
    const int aoff0 = Ra * 64 + ((quad       ^ (Ra & 7)) << 3);
    const int aoff1 = Ra * 64 + (((4 + quad) ^ (Ra & 7)) << 3);
    const int Rb = wn + l16;
    const int boff0 = Rb * 64 + ((quad       ^ (Rb & 7)) << 3);
    const int boff1 = Rb * 64 + (((4 + quad) ^ (Rb & 7)) << 3);

    for (int k0 = 0; k0 < K; k0 += 64) {
        __syncthreads();
#pragma unroll
        for (int c = 0; c < 4; c++)
            gload_lds16(pA + c * cstep + k0, &As[c * 2048 + wave * 512]);
#pragma unroll
        for (int c = 0; c < 2; c++)
            gload_lds16(pB + c * cstep + k0, &Bs[c * 2048 + wave * 512]);
        __syncthreads();

        short8 af0[4], af1[4];
#pragma unroll
        for (int i = 0; i < 4; i++) {
            af0[i] = *(const short8*)&As[aoff0 + i * 1024];
            af1[i] = *(const short8*)&As[aoff1 + i * 1024];
        }
#pragma unroll
        for (int j = 0; j < 2; j++) {
            const short8 bf0 = *(const short8*)&Bs[boff0 + j * 1024];
            const short8 bf1 = *(const short8*)&Bs[boff1 + j * 1024];
#pragma unroll
            for (int i = 0; i < 4; i++) {
                acc[i][j] = __builtin_amdgcn_mfma_f32_16x16x32_bf16(af0[i], bf0, acc[i][j], 0, 0, 0);
                acc[i][j] = __builtin_amdgcn_mfma_f32_16x16x32_bf16(af1[i], bf1, acc[i][j], 0, 0, 0);
            }
        }
    }

#pragma unroll
    for (int i = 0; i < 4; i++) {
#pragma unroll
        for (int j = 0; j < 2; j++) {
#pragma unroll
            for (int r = 0; r < 4; r++) {
                const int row = m0 + wm + i * 16 + quad * 4 + r;
                const int col = n0 + wn + j * 16 + l16;
                Cout[(size_t)row * N + col] = acc[i][j][r] + bias[col];
            }
        }
    }
}

// ===== legacy fused-cvt GEMM (fallback when ws < 48MB) =====
template <int MODE, int AFP32>
__global__ __launch_bounds__(256, 2) void gemm_bt(
    const void* __restrict__ Av, const float* __restrict__ W,
    const float* __restrict__ bias,
    ushort* __restrict__ Cq, ushort* __restrict__ Ck, ushort* __restrict__ Cv,
    float* __restrict__ Cout, int M, int N, int K)
{
    __shared__ __align__(16) ushort As[128 * LDS_STRIDE];
    __shared__ __align__(16) ushort Bs[128 * LDS_STRIDE];

    const int tid  = threadIdx.x;
    const int lane = tid & 63;
    const int wave = tid >> 6;
    const int wm = (wave >> 1) * 64;
    const int wn = (wave & 1) * 64;
    const int m0 = blockIdx.x * 128;
    const int n0 = blockIdx.y * 128;
    const int quad = lane >> 4;
    const int l16  = lane & 15;

    floatx4 acc[4][4];
#pragma unroll
    for (int i = 0; i < 4; i++)
#pragma unroll
        for (int j = 0; j < 4; j++) acc[i][j] = (floatx4)0.0f;

    const int srow = tid >> 2;
    const int scol = (tid & 3) * 8;

    for (int k0 = 0; k0 < K; k0 += 32) {
        short8 a0, a1;
        if (AFP32) {
            const float* A = (const float*)Av;
            a0 = cvt8(A + (size_t)(m0 + srow) * K + k0 + scol);
            a1 = cvt8(A + (size_t)(m0 + srow + 64) * K + k0 + scol);
        } else {
            const ushort* A = (const ushort*)Av;
            a0 = *(const short8*)(A + (size_t)(m0 + srow) * K + k0 + scol);
            a1 = *(const short8*)(A + (size_t)(m0 + srow + 64) * K + k0 + scol);
        }
        const short8 b0 = cvt8(W + (size_t)(n0 + srow) * K + k0 + scol);
        const short8 b1 = cvt8(W + (size_t)(n0 + srow + 64) * K + k0 + scol);
        __syncthreads();
        *(short8*)&As[srow * LDS_STRIDE + scol] = a0;
        *(short8*)&As[(srow + 64) * LDS_STRIDE + scol] = a1;
        *(short8*)&Bs[srow * LDS_STRIDE + scol] = b0;
        *(short8*)&Bs[(srow + 64) * LDS_STRIDE + scol] = b1;
        __syncthreads();

        short8 af[4], bf[4];
#pragma unroll
        for (int i = 0; i < 4; i++)
            af[i] = *(const short8*)&As[(wm + i * 16 + l16) * LDS_STRIDE + quad * 8];
#pragma unroll
        for (int j = 0; j < 4; j++)
            bf[j] = *(const short8*)&Bs[(wn + j * 16 + l16) * LDS_STRIDE + quad * 8];
#pragma unroll
        for (int i = 0; i < 4; i++)
#pragma unroll
            for (int j = 0; j < 4; j++)
                acc[i][j] = __builtin_amdgcn_mfma_f32_16x16x32_bf16(af[i], bf[j], acc[i][j], 0, 0, 0);
    }

#pragma unroll
    for (int i = 0; i < 4; i++) {
#pragma unroll
        for (int j = 0; j < 4; j++) {
#pragma unroll
            for (int r = 0; r < 4; r++) {
                const int row = m0 + wm + i * 16 + quad * 4 + r;
                const int col = n0 + wn + j * 16 + l16;
                float v = acc[i][j][r] + bias[col];
                if (MODE == 0) {
                    const int h  = col / 192;
                    const int rr = col - h * 192;
                    const int sel = rr >> 6;
                    const int d   = rr & 63;
                    const int b = row >> 11;
                    const int t = row & 2047;
                    const int bh = b * 16 + h;
                    if (sel == 0) {
                        Cq[(((size_t)bh) * 2048 + t) * 64 + d] =
                            f32_to_bf16(v * Q_PRESCALE);
                    } else if (sel == 1) {
                        Ck[(((size_t)bh) * 2048 + t) * 64 + d] = f32_to_bf16(v);
                    } else {
                        Cv[(((size_t)bh * 32 + (t >> 6)) * 64 + d) * 64 + v_slot(t & 63)] =
                            f32_to_bf16(v);
                    }
                } else {
                    Cout[(size_t)row * N + col] = v;
                }
            }
        }
    }
}

// ===========================================================================
// MFMA causal flash attention, v12 (unchanged): 64-row q-blocks, 4 blocks/CU,
// KVBLK=64 dbuf LDS 32KB, per-CU step count exactly constant, swapped QK^T
// register-P body, kf/vf lifetime split. Grid 1024 = 32 bh x 32 qtiles.
// ===========================================================================
__global__ __launch_bounds__(256, 4) void attn_mfma(
    const ushort* __restrict__ Q, const ushort* __restrict__ K,
    const ushort* __restrict__ Vtb, ushort* __restrict__ O)
{
    const int bid   = blockIdx.x;
    const int bh    = bid & 31;
    const int qtIdx = bid >> 5;                       // 0..31
    const int qi    = (qtIdx < 16) ? (31 - qtIdx) : (qtIdx - 16);
    const int tid  = threadIdx.x;
    const int wave = tid >> 6;
    const int lane = tid & 63;
    const int quad = lane >> 4;
    const int l16  = lane & 15;
    const int qb   = qi * 64 + wave * 16;

    __shared__ __align__(16) ushort Ks[2][4096];  // 64 keys x 64 ush (swz)
    __shared__ __align__(16) ushort Vs[2][4096];

    const size_t kbase = (size_t)bh * 2048 * 64;

    const int ob0 = tid * 16, ob1 = ob0 + 4096;
    const int r0 = ob0 >> 7, c0 = (ob0 >> 4) & 7;
    const int r1 = ob1 >> 7, c1 = (ob1 >> 4) & 7;
    const int e0 = r0 * 64 + ((c0 ^ (r0 & 7)) << 3);  // ushort idx in tile
    const int e1 = r1 * 64 + ((c1 ^ (r1 & 7)) << 3);
    const ushort* Kb = K + kbase;                      // + t*4096 + e
    const ushort* Vb = Vtb + (size_t)bh * 32 * 4096;   // + t*4096 + e

    auto stage = [&](int t, ushort* KsB, ushort* VsB) {
        const ushort* Ktile = Kb + t * 4096;
        const ushort* Vtile = Vb + t * 4096;
        gload_lds16(Ktile + e0, KsB + wave * 512);
        gload_lds16(Ktile + e1, KsB + 2048 + wave * 512);
        gload_lds16(Vtile + e0, VsB + wave * 512);
        gload_lds16(Vtile + e1, VsB + 2048 + wave * 512);
    };

    const int sw0 = ((quad ^ (l16 & 7)) << 3);        // half 0: C = quad
    const int sw1 = (((4 + quad) ^ (l16 & 7)) << 3);  // half 1: C = 4+quad
    const int rbase = l16 * 64;

    short8 qf0, qf1;
    {
        const ushort* qp = Q + kbase + (size_t)(qb + l16) * 64 + quad * 8;
        qf0 = *(const short8*)qp;
        qf1 = *(const short8*)(qp + 32);
    }

    floatx4 accO[4];
#pragma unroll
    for (int d = 0; d < 4; d++) accO[d] = (floatx4)0.0f;
    float accLs = 0.0f;

    union PB { unsigned int u[4]; short8 s8; };

    auto compute = [&](int t, const ushort* KsB, const ushort* VsB) {
        short8 kf[4][2];
#pragma unroll
        for (int j = 0; j < 4; j++) {
            kf[j][0] = *(const short8*)&KsB[j * 1024 + rbase + sw0];
            kf[j][1] = *(const short8*)&KsB[j * 1024 + rbase + sw1];
        }
        floatx4 sc[4];
#pragma unroll
        for (int j = 0; j < 4; j++) {
            floatx4 acc = (floatx4)0.0f;
            acc = __builtin_amdgcn_mfma_f32_16x16x32_bf16(kf[j][0], qf0, acc, 0, 0, 0);
            acc = __builtin_amdgcn_mfma_f32_16x16x32_bf16(kf[j][1], qf1, acc, 0, 0, 0);
            sc[j] = acc;
        }
        if (t * 64 + 63 > qb) {  // diagonal tile: causal mask
            const int qcol = qb + l16;
#pragma unroll
            for (int j = 0; j < 4; j++) {
                const int keyb = t * 64 + j * 16 + quad * 4;
#pragma unroll
                for (int r = 0; r < 4; r++)
                    if (keyb + r > qcol) sc[j][r] = -1e30f;
            }
        }
#pragma unroll
        for (int j = 0; j < 4; j++)
#pragma unroll
            for (int r = 0; r < 4; r++)
                sc[j][r] = __builtin_amdgcn_exp2f(sc[j][r]);
        const floatx4 ssum = sc[0] + sc[1] + sc[2] + sc[3];
        accLs += (ssum[0] + ssum[1]) + (ssum[2] + ssum[3]);
        PB p0, p1;
#pragma unroll
        for (int j = 0; j < 2; j++) {
            p0.u[j * 2 + 0] = cvtpk(sc[j][0], sc[j][1]);
            p0.u[j * 2 + 1] = cvtpk(sc[j][2], sc[j][3]);
            p1.u[j * 2 + 0] = cvtpk(sc[j + 2][0], sc[j + 2][1]);
            p1.u[j * 2 + 1] = cvtpk(sc[j + 2][2], sc[j + 2][3]);
        }
        short8 vf[4][2];
#pragma unroll
        for (int d = 0; d < 4; d++) {
            vf[d][0] = *(const short8*)&VsB[d * 1024 + rbase + sw0];
            vf[d][1] = *(const short8*)&VsB[d * 1024 + rbase + sw1];
        }
#pragma unroll
        for (int d = 0; d < 4; d++) {
            accO[d] = __builtin_amdgcn_mfma_f32_16x16x32_bf16(p0.s8, vf[d][0], accO[d], 0, 0, 0);
            accO[d] = __builtin_amdgcn_mfma_f32_16x16x32_bf16(p1.s8, vf[d][1], accO[d], 0, 0, 0);
        }
    };

    const int nt = qi + 1;  // 64-key steps
    stage(0, Ks[0], Vs[0]);
    __syncthreads();        // buf0 staged
    int t = 0;
    while (true) {
        if (t + 1 < nt) stage(t + 1, Ks[1], Vs[1]);  // prefetch under compute
        compute(t, Ks[0], Vs[0]);
        __syncthreads();    // prefetch landed + all waves done with buf0
        if (++t >= nt) break;
        if (t + 1 < nt) stage(t + 1, Ks[0], Vs[0]);
        compute(t, Ks[1], Vs[1]);
        __syncthreads();
        if (++t >= nt) break;
    }

    const int b = bh >> 4, h = bh & 15;
    {
        float L = accLs;
        L += __shfl_xor(L, 16);
        L += __shfl_xor(L, 32);  // now L(q=l16) in all quads
        float inv[4];
#pragma unroll
        for (int r = 0; r < 4; r++) inv[r] = 1.0f / __shfl(L, quad * 4 + r);
#pragma unroll
        for (int d = 0; d < 4; d++)
#pragma unroll
            for (int r = 0; r < 4; r++)
                O[(size_t)(b * 2048 + qb + quad * 4 + r) * 1024 + h * 64 + d * 16 + l16] =
                    f32_to_bf16(accO[d][r] * inv[r]);
    }
}

extern "C" void kernel_launch(void* const* d_in, const int* in_sizes, int n_in,
                              void* d_out, int out_size, void* d_ws, size_t ws_size,
                              hipStream_t stream) {
    const float* x    = (const float*)d_in[0];
    const float* Wqkv = (const float*)d_in[1];
    const float* bqkv = (const float*)d_in[2];
    const float* Wout = (const float*)d_in[3];
    const float* bout = (const float*)d_in[4];
    float* out = (float*)d_out;

    char* ws = (char*)d_ws;
    const size_t MB = 1024 * 1024;
    ushort* Q    = (ushort*)(ws + 0 * MB);
    ushort* Kk   = (ushort*)(ws + 8 * MB);
    ushort* Vtb  = (ushort*)(ws + 16 * MB);  // tile-blocked permuted V (direct)
    ushort* O    = (ushort*)(ws + 24 * MB);

    const dim3 blk(256);
    if (ws_size >= 48 * MB) {
        ushort* xb    = (ushort*)(ws + 32 * MB);
        ushort* Wqkvb = (ushort*)(ws + 40 * MB);
        ushort* Woutb = (ushort*)(ws + 46 * MB);
        cvt_bf16_3<<<dim3(4096), blk, 0, stream>>>(x, Wqkv, Wout, xb, Wqkvb, Woutb);
        gemm_qkv<<<dim3(32, 24), blk, 0, stream>>>(xb, Wqkvb, bqkv, Q, Kk, Vtb,
                                                   4096, 3072, 1024);
        attn_mfma<<<dim3(1024), blk, 0, stream>>>(Q, Kk, Vtb, O);
        gemm_out<<<dim3(32, 16), blk, 0, stream>>>(O, Woutb, bout, out,
                                                   4096, 1024, 1024);
    } else {
        gemm_bt<0, 1><<<dim3(32, 24), blk, 0, stream>>>(x, Wqkv, bqkv, Q, Kk, Vtb,
                                                        nullptr, 4096, 3072, 1024);
        attn_mfma<<<dim3(1024), blk, 0, stream>>>(Q, Kk, Vtb, O);
        gemm_bt<1, 0><<<dim3(32, 8), blk, 0, stream>>>(O, Wout, bout, nullptr, nullptr,
                                                       nullptr, out, 4096, 1024, 1024);
    }
}